// Round 4
// baseline (694.922 us; speedup 1.0000x reference)
//
#include <hip/hip_runtime.h>
#include <hip/hip_bf16.h>
#include <hip/hip_fp16.h>

constexpr int INC  = 32;
constexpr int OUTC = 32;
constexpr int CAP  = 80;   // max contributions kept per output row; lambda=27,
                           // P(deg>80) ~ 1e-15/row (Chernoff) -> negligible.

typedef __bf16 bf16x8 __attribute__((ext_vector_type(8)));
typedef float  f32x4  __attribute__((ext_vector_type(4)));

static __device__ __forceinline__ uint32_t f2bf_bits(float f) {
    uint32_t u = __float_as_uint(f);
    return (u + 0x7FFFu + ((u >> 16) & 1u)) >> 16;   // RNE to bf16
}

// ---------------------------------------------------------------------------
// Phase 1: Y[e] = feats[in_idx[e]] @ W_k  (bf16 rows, coalesced 64B writes)
// plus bump-binning of entry ids by out_idx (u32 atomics, 1 per entry).
// R1-R3 showed float scatter atomics cap at ~300G ops/s; this kernel has 16x
// fewer atomics and they're u32 counter bumps overlapped with streaming.
// B-fragments column-permuted: acc0 -> ch 2c, acc1 -> ch 2c+1 so each lane
// packs one bf16x2 dword per D row.
// ---------------------------------------------------------------------------
__global__ __launch_bounds__(256) void compute_y_bin(
    const float* __restrict__ feats,    // [N][32]
    const float* __restrict__ wkern,    // [K][32][32]
    const int*   __restrict__ in_idx,   // [K][N]
    const int*   __restrict__ out_idx,  // [K][N]
    uint32_t*    __restrict__ Y,        // [K*N][16] bf16x2
    uint32_t*    __restrict__ bucket,   // [N][CAP] entry ids
    uint32_t*    __restrict__ count,    // [N] (pre-zeroed)
    int N)
{
    const int k    = blockIdx.y;
    const int lane = threadIdx.x & 63;
    const int col  = lane & 15;
    const int quad = lane >> 4;

    const int wave   = blockIdx.x * 4 + (threadIdx.x >> 6);
    const int nwaves = gridDim.x * 4;

    const float* wk = wkern + (size_t)k * (INC * OUTC);
    bf16x8 b0, b1;
#pragma unroll
    for (int j = 0; j < 8; ++j) {
        const int kk = quad * 8 + j;
        b0[j] = (__bf16)wk[kk * OUTC + 2 * col];
        b1[j] = (__bf16)wk[kk * OUTC + 2 * col + 1];
    }

    const int  kN     = k * N;
    const int* iin_p  = in_idx  + (size_t)kN;
    const int* iout_p = out_idx + (size_t)kN;
    const int  ntiles = N >> 4;

    for (int t = wave; t < ntiles; t += nwaves) {
        const int base = t << 4;

        const int iin = iin_p[base + col];      // A row m = col

        const float4* ap = (const float4*)(feats + (size_t)iin * INC + quad * 8);
        const float4 a_lo = ap[0];
        const float4 a_hi = ap[1];
        bf16x8 a;
        a[0] = (__bf16)a_lo.x; a[1] = (__bf16)a_lo.y;
        a[2] = (__bf16)a_lo.z; a[3] = (__bf16)a_lo.w;
        a[4] = (__bf16)a_hi.x; a[5] = (__bf16)a_hi.y;
        a[6] = (__bf16)a_hi.z; a[7] = (__bf16)a_hi.w;

        f32x4 acc0 = {0.f, 0.f, 0.f, 0.f};
        f32x4 acc1 = {0.f, 0.f, 0.f, 0.f};
        acc0 = __builtin_amdgcn_mfma_f32_16x16x32_bf16(a, b0, acc0, 0, 0, 0);
        acc1 = __builtin_amdgcn_mfma_f32_16x16x32_bf16(a, b1, acc1, 0, 0, 0);

        // Y rows: D row m = quad*4+r, lane covers channels (2c, 2c+1).
#pragma unroll
        for (int r = 0; r < 4; ++r) {
            const int e = kN + base + quad * 4 + r;
            Y[(size_t)e * 16 + col] =
                (f2bf_bits(acc1[r]) << 16) | f2bf_bits(acc0[r]);
        }

        // Binning: 16 lanes (col<4) each claim a slot for row m = quad*4+col.
        if (col < 4) {
            const int m    = quad * 4 + col;
            const int iout = iout_p[base + m];
            const uint32_t slot = atomicAdd(count + iout, 1u);
            if (slot < CAP) bucket[(size_t)iout * CAP + slot] = (uint32_t)(kN + base + m);
        }
    }
}

// ---------------------------------------------------------------------------
// Phase 2: out[j] = BN_ReLU( sum_{e in bucket[j]} Y[e] ).  16 lanes per row
// (lane = bf16x2 channel pair). Entry loads pipelined 4-deep to cover the
// ~500cyc random-64B-line latency.
// ---------------------------------------------------------------------------
__global__ __launch_bounds__(256) void gather_bn_relu(
    const uint32_t* __restrict__ Y,       // [K*N][16]
    const uint32_t* __restrict__ bucket,  // [N][CAP]
    const uint32_t* __restrict__ count,   // [N]
    float*          __restrict__ out,     // [N][32]
    const float* __restrict__ gamma,
    const float* __restrict__ beta,
    const float* __restrict__ mean,
    const float* __restrict__ var,
    int N)
{
    const int lane16 = threadIdx.x & 15;
    const int grp    = (blockIdx.x * blockDim.x + threadIdx.x) >> 4;
    const int ngrp   = (gridDim.x * blockDim.x) >> 4;

    const int c0 = 2 * lane16;
    const float s0 = gamma[c0]     * rsqrtf(var[c0]     + 1e-5f);
    const float s1 = gamma[c0 + 1] * rsqrtf(var[c0 + 1] + 1e-5f);
    const float q0 = beta[c0]     - mean[c0]     * s0;
    const float q1 = beta[c0 + 1] - mean[c0 + 1] * s1;

    for (int j = grp; j < N; j += ngrp) {
        const int cnt = (int)min(count[j], (uint32_t)CAP);
        const uint32_t* bk = bucket + (size_t)j * CAP;

        float a0 = 0.f, a1 = 0.f;
        int e = 0;
        for (; e + 4 <= cnt; e += 4) {
            const uint32_t e0 = bk[e], e1 = bk[e + 1], e2 = bk[e + 2], e3 = bk[e + 3];
            const uint32_t v0 = Y[(size_t)e0 * 16 + lane16];
            const uint32_t v1 = Y[(size_t)e1 * 16 + lane16];
            const uint32_t v2 = Y[(size_t)e2 * 16 + lane16];
            const uint32_t v3 = Y[(size_t)e3 * 16 + lane16];
            a0 += __uint_as_float(v0 << 16);           a1 += __uint_as_float(v0 & 0xffff0000u);
            a0 += __uint_as_float(v1 << 16);           a1 += __uint_as_float(v1 & 0xffff0000u);
            a0 += __uint_as_float(v2 << 16);           a1 += __uint_as_float(v2 & 0xffff0000u);
            a0 += __uint_as_float(v3 << 16);           a1 += __uint_as_float(v3 & 0xffff0000u);
        }
        for (; e < cnt; ++e) {
            const uint32_t v = Y[(size_t)bk[e] * 16 + lane16];
            a0 += __uint_as_float(v << 16);
            a1 += __uint_as_float(v & 0xffff0000u);
        }

        float2 o;
        o.x = fmaxf(fmaf(a0, s0, q0), 0.0f);
        o.y = fmaxf(fmaf(a1, s1, q1), 0.0f);
        ((float2*)out)[(size_t)j * 16 + lane16] = o;
    }
}

// ------------------- fallback: R3 pk16 scatter path ------------------------
__global__ __launch_bounds__(256) void scatter_conv_mfma_pk(
    const float* __restrict__ feats,
    const float* __restrict__ wkern,
    const int*   __restrict__ in_idx,
    const int*   __restrict__ out_idx,
    __half2*     __restrict__ ws,
    int N)
{
    const int k    = blockIdx.y;
    const int lane = threadIdx.x & 63;
    const int col  = lane & 15;
    const int quad = lane >> 4;
    const int wave   = blockIdx.x * 4 + (threadIdx.x >> 6);
    const int nwaves = gridDim.x * 4;

    const float* wk = wkern + (size_t)k * (INC * OUTC);
    bf16x8 b0, b1;
#pragma unroll
    for (int j = 0; j < 8; ++j) {
        const int kk = quad * 8 + j;
        b0[j] = (__bf16)wk[kk * OUTC + 2 * col];
        b1[j] = (__bf16)wk[kk * OUTC + 2 * col + 1];
    }

    const int* iin_p  = in_idx  + (size_t)k * N;
    const int* iout_p = out_idx + (size_t)k * N;
    const int  ntiles = N >> 4;

    for (int t = wave; t < ntiles; t += nwaves) {
        const int base = t << 4;
        const int iin = iin_p[base + col];
        int orow[4];
#pragma unroll
        for (int r = 0; r < 4; ++r) orow[r] = iout_p[base + quad * 4 + r];

        const float4* ap = (const float4*)(feats + (size_t)iin * INC + quad * 8);
        const float4 a_lo = ap[0];
        const float4 a_hi = ap[1];
        bf16x8 a;
        a[0] = (__bf16)a_lo.x; a[1] = (__bf16)a_lo.y;
        a[2] = (__bf16)a_lo.z; a[3] = (__bf16)a_lo.w;
        a[4] = (__bf16)a_hi.x; a[5] = (__bf16)a_hi.y;
        a[6] = (__bf16)a_hi.z; a[7] = (__bf16)a_hi.w;

        f32x4 acc0 = {0.f, 0.f, 0.f, 0.f};
        f32x4 acc1 = {0.f, 0.f, 0.f, 0.f};
        acc0 = __builtin_amdgcn_mfma_f32_16x16x32_bf16(a, b0, acc0, 0, 0, 0);
        acc1 = __builtin_amdgcn_mfma_f32_16x16x32_bf16(a, b1, acc1, 0, 0, 0);

#pragma unroll
        for (int r = 0; r < 4; ++r) {
            __half2 v = __halves2half2(__float2half(acc0[r]), __float2half(acc1[r]));
            unsafeAtomicAdd(ws + (size_t)orow[r] * 16 + col, v);
        }
    }
}

__global__ __launch_bounds__(256) void bn_relu_f16(
    const __half2* __restrict__ ws,
    float* __restrict__ out,
    const float* __restrict__ gamma,
    const float* __restrict__ beta,
    const float* __restrict__ mean,
    const float* __restrict__ var,
    int total2)
{
    const int tid    = blockIdx.x * blockDim.x + threadIdx.x;
    const int stride = gridDim.x * blockDim.x;
    const int p      = tid & 15;
    const int c0     = 2 * p;

    const float s0 = gamma[c0]     * rsqrtf(var[c0]     + 1e-5f);
    const float s1 = gamma[c0 + 1] * rsqrtf(var[c0 + 1] + 1e-5f);
    const float q0 = beta[c0]     - mean[c0]     * s0;
    const float q1 = beta[c0 + 1] - mean[c0 + 1] * s1;

    float2* po = (float2*)out;
    for (int i = tid; i < total2; i += stride) {
        const __half2 h = ws[i];
        float2 v;
        v.x = fmaxf(fmaf(__low2float(h),  s0, q0), 0.0f);
        v.y = fmaxf(fmaf(__high2float(h), s1, q1), 0.0f);
        po[i] = v;
    }
}

extern "C" void kernel_launch(void* const* d_in, const int* in_sizes, int n_in,
                              void* d_out, int out_size, void* d_ws, size_t ws_size,
                              hipStream_t stream) {
    const float* feats   = (const float*)d_in[0];
    const float* wkern   = (const float*)d_in[1];
    const float* gamma   = (const float*)d_in[2];
    const float* beta    = (const float*)d_in[3];
    const float* mean    = (const float*)d_in[4];
    const float* var     = (const float*)d_in[5];
    const int*   in_idx  = (const int*)d_in[6];
    const int*   out_idx = (const int*)d_in[7];
    float*       out     = (float*)d_out;

    const int N = in_sizes[0] / INC;                  // 400000
    const int K = in_sizes[1] / (INC * OUTC);         // 27

    const size_t ybytes = (size_t)K * N * OUTC * 2;   // 691.2 MB bf16
    const size_t bbytes = (size_t)N * CAP * 4;        // 128   MB
    const size_t cbytes = (size_t)N * 4;              // 1.6   MB

    if (ws_size >= ybytes + bbytes + cbytes) {
        uint32_t* Y      = (uint32_t*)d_ws;
        uint32_t* bucket = (uint32_t*)((char*)d_ws + ybytes);
        uint32_t* count  = (uint32_t*)((char*)d_ws + ybytes + bbytes);

        hipMemsetAsync(count, 0, cbytes, stream);

        dim3 grid(80, K);
        compute_y_bin<<<grid, 256, 0, stream>>>(feats, wkern, in_idx, out_idx,
                                                Y, bucket, count, N);

        gather_bn_relu<<<2048, 256, 0, stream>>>(Y, bucket, count, out,
                                                 gamma, beta, mean, var, N);
    } else {
        // R3 path: packed-fp16 scatter atomics (needs 25.6 MB ws).
        __half2* acc = (__half2*)d_ws;
        hipMemsetAsync(acc, 0, (size_t)N * OUTC * sizeof(__half), stream);
        dim3 grid(80, K);
        scatter_conv_mfma_pk<<<grid, 256, 0, stream>>>(feats, wkern, in_idx, out_idx, acc, N);
        bn_relu_f16<<<1024, 256, 0, stream>>>(acc, out, gamma, beta, mean, var, N * 16);
    }
}